// Round 14
// baseline (152.550 us; speedup 1.0000x reference)
//
#include <hip/hip_runtime.h>

typedef float f32x4 __attribute__((ext_vector_type(4)));

// Problem constants (from reference setup_inputs)
constexpr int B  = 4;
constexpr int M  = 1088;
constexpr int HH = 32;
constexpr int D  = 128;
constexpr int F  = 128;
constexpr int C  = 512;

constexpr int SZ_YNUM = B * C * HH * D;   // 8388608
constexpr int SZ_YDEN = B * C * HH;       // 65536
constexpr int SZ_KVM  = B * M * HH * D;   // 17825792
constexpr int SZ_H    = B * HH * F * D;   // 2097152

constexpr int OFF_YNUM = 0;
constexpr int OFF_YDEN = OFF_YNUM + SZ_YNUM;
constexpr int OFF_K    = OFF_YDEN + SZ_YDEN;
constexpr int OFF_V    = OFF_K + SZ_KVM;
constexpr int OFF_FK   = OFF_V + SZ_KVM;
constexpr int OFF_H    = OFF_FK + SZ_KVM;
constexpr int OFF_S    = OFF_H + SZ_H;

constexpr int INNER4      = HH * D / 4;           // 1024 f32x4 per (b,m) row
constexpr int ROWS_PER_CB = 4;                    // 64 KB per copy block
constexpr int COPY_BLOCKS = B * M / ROWS_PER_CB;  // 1088 (exact)
constexpr int HS_BLOCKS   = B * HH * 2;           // 256
constexpr int Y_BLOCKS    = B * HH * 8;           // 1024
constexpr int ESTEP       = 16;

__device__ __forceinline__ void ring_params(const int* wp_p, const int* valid_p,
                                            int& wp, int& num_excess, int& pos) {
    wp = *wp_p;
    int valid = *valid_p;
    if (valid + C <= M) {
        num_excess = 0;
        pos = (wp + valid) % M;
    } else {
        num_excess = valid + C - M;
        pos = (wp + num_excess) % M;
    }
}

// ---------------------------------------------------------------------------
// One copy block = ROWS_PER_CB (b,m)-rows of one (B,M,HH,128) tensor.
// ---------------------------------------------------------------------------
__device__ __forceinline__ void ring_copy_block(int cb, int tid,
                                                const f32x4* __restrict__ src,
                                                const f32x4* __restrict__ chk,
                                                f32x4* __restrict__ dst,
                                                int pos) {
    int bm0 = cb * ROWS_PER_CB;
#pragma unroll
    for (int r = 0; r < ROWS_PER_CB; ++r) {
        int bm = bm0 + r;
        int m = bm % M;
        int b = bm / M;
        int off = m - pos;
        if (off < 0) off += M;
        const f32x4* s = (off < C) ? &chk[(b * C + off) * INNER4]
                                   : &src[bm * INNER4];
        f32x4* d = &dst[bm * INNER4];
#pragma unroll
        for (int k = 0; k < INNER4 / 256; ++k)
            d[k * 256 + tid] = s[k * 256 + tid];
    }
}

// ---------------------------------------------------------------------------
// update_hs body (R4 shape: 256 blocks, 64f x 128d tile, 13 KB LDS) with
// DEPTH-2 register prefetch: two register tile-sets A/B, single LDS buffer.
// Steady state keeps loads for tiles t+1 AND t+2 in flight -> iteration time
// ~max(compute, L/2) instead of ~L under copy-saturated HBM.
// ---------------------------------------------------------------------------
__device__ void update_hs_body(int bx,
                               const float* __restrict__ FKi,
                               const float* __restrict__ Vi,
                               const float* __restrict__ Hi,
                               const float* __restrict__ Si,
                               float* __restrict__ Ho,
                               float* __restrict__ So,
                               int wp, int num_excess) {
    const int tid = threadIdx.x;
    const int fhalf = bx & 1;
    const int bh = bx >> 1;
    const int h = bh & (HH - 1);
    const int b = bh >> 5;
    const int fbase = fhalf * 64;

    __shared__ float  fk_s[ESTEP][64];   // 4 KB
    __shared__ f32x4  v_s[ESTEP][32];    // 8 KB
    __shared__ float  sred[4][64];       // 1 KB

    const int tf = tid >> 5;   // 0..7  (8 f-rows each)
    const int td = tid & 31;   // 0..31 (d quads)
    const int cq = tid & 63;   // fk column / s column
    const int qq = tid >> 6;   // quarter

    f32x4 acc[8];
#pragma unroll
    for (int i = 0; i < 8; ++i) acc[i] = (f32x4)0.f;
    float s_part = 0.f;

    float fkA[4], fkB[4];
    f32x4 vA[2],  vB[2];

    auto load_tile = [&](int e0, float* fk_r, f32x4* v_r) {
#pragma unroll
        for (int j = 0; j < 4; ++j) {
            int e = e0 + qq + 4 * j;
            int me = wp + e;
            if (me >= M) me -= M;
            if (me >= M) me -= M;
            float v = 0.f;
            if (e < num_excess) v = FKi[((b * M + me) * HH + h) * F + fbase + cq];
            fk_r[j] = v;
        }
#pragma unroll
        for (int j = 0; j < 2; ++j) {
            int e = e0 + tf + 8 * j;
            int me = wp + e;
            if (me >= M) me -= M;
            if (me >= M) me -= M;
            f32x4 v = (f32x4)0.f;
            if (e < num_excess) v = *(const f32x4*)&Vi[((b * M + me) * HH + h) * D + td * 4];
            v_r[j] = v;
        }
    };
    auto store_tile = [&](const float* fk_r, const f32x4* v_r) {
#pragma unroll
        for (int j = 0; j < 4; ++j) fk_s[qq + 4 * j][cq] = fk_r[j];
#pragma unroll
        for (int j = 0; j < 2; ++j) v_s[tf + 8 * j][td] = v_r[j];
    };
    auto compute = [&]() {
#pragma unroll
        for (int ee = 0; ee < ESTEP; ++ee) {
            f32x4 fa = *(const f32x4*)&fk_s[ee][tf * 8];
            f32x4 fb = *(const f32x4*)&fk_s[ee][tf * 8 + 4];
            f32x4 vv = v_s[ee][td];
            acc[0] += fa.x * vv; acc[1] += fa.y * vv;
            acc[2] += fa.z * vv; acc[3] += fa.w * vv;
            acc[4] += fb.x * vv; acc[5] += fb.y * vv;
            acc[6] += fb.z * vv; acc[7] += fb.w * vv;
        }
#pragma unroll
        for (int j = 0; j < 4; ++j) s_part += fk_s[qq * 4 + j][cq];
    };

    if (num_excess > 0) {
        const int nt = (num_excess + ESTEP - 1) / ESTEP;
        load_tile(0, fkA, vA);                       // tile 0 -> A
        if (nt > 1) load_tile(ESTEP, fkB, vB);       // tile 1 -> B (in flight)
        store_tile(fkA, vA);                         // LDS <- tile 0
        for (int t = 0; t < nt; t += 2) {
            __syncthreads();                         // tile t visible
            if (t + 2 < nt) load_tile((t + 2) * ESTEP, fkA, vA);  // A free
            compute();                               // tile t
            __syncthreads();                         // reads done
            if (t + 1 >= nt) break;
            store_tile(fkB, vB);                     // LDS <- tile t+1
            __syncthreads();                         // tile t+1 visible
            if (t + 3 < nt) load_tile((t + 3) * ESTEP, fkB, vB);  // B free
            compute();                               // tile t+1
            __syncthreads();                         // reads done
            if (t + 2 >= nt) break;
            store_tile(fkA, vA);                     // LDS <- tile t+2
        }
    }

    // S_new
    sred[qq][cq] = s_part;
    __syncthreads();
    if (tid < 64) {
        int f = fbase + tid;
        int si = (b * HH + h) * F + f;
        So[si] = Si[si] + sred[0][tid] + sred[1][tid] + sred[2][tid] + sred[3][tid];
    }

    // H_new = H_old + acc
#pragma unroll
    for (int i = 0; i < 8; ++i) {
        int f = fbase + tf * 8 + i;
        int base = ((b * HH + h) * F + f) * D + td * 4;
        f32x4 hold = *(const f32x4*)&Hi[base];
        *(f32x4*)&Ho[base] = hold + acc[i];
    }
}

// ---------------------------------------------------------------------------
// compute_y_den body: block bx in [0,1024). 64(c) x 128(d) tile, f-step 32.
// (R4-proven version, unchanged.)
// ---------------------------------------------------------------------------
__device__ void compute_y_den_body(int bx,
                                   const float* __restrict__ fq,
                                   const float* __restrict__ Hn,
                                   const float* __restrict__ Sn,
                                   float* __restrict__ ynum,
                                   float* __restrict__ yden) {
    const int tid = threadIdx.x;
    int t0 = bx;
    const int ct = t0 & 7; t0 >>= 3;
    const int h = t0 & (HH - 1);
    const int b = t0 >> 5;
    const int c0 = ct * 64;
    const int bh = b * HH + h;

    __shared__ float  fq_s[32][65];   // [ee][c], padded
    __shared__ f32x4  h_s[32][32];    // [ee][d4]
    __shared__ float  S_s[128];
    __shared__ float  den_s[64][4];

    const int tc = tid >> 5;  // 0..7 (8 c-rows each)
    const int td = tid & 31;  // 0..31 (d quads)
    const int cq = tid & 63;
    const int qq = tid >> 6;

    if (tid < 128) S_s[tid] = Sn[bh * F + tid];

    f32x4 acc[8];
#pragma unroll
    for (int i = 0; i < 8; ++i) acc[i] = (f32x4)0.f;
    float den_part = 0.f;

    for (int f0 = 0; f0 < F; f0 += 32) {
#pragma unroll
        for (int r = 0; r < 8; ++r) {
            int idx = tid + r * 256;
            int cc = idx >> 5, ee = idx & 31;
            fq_s[ee][cc] = fq[((b * C + c0 + cc) * HH + h) * F + f0 + ee];
        }
#pragma unroll
        for (int r = 0; r < 4; ++r) {
            int idx = tid + r * 256;
            int row = idx >> 5, col = idx & 31;
            h_s[row][col] = *(const f32x4*)&Hn[(bh * F + f0 + row) * D + col * 4];
        }
        __syncthreads();
#pragma unroll
        for (int ee = 0; ee < 32; ++ee) {
            f32x4 hv = h_s[ee][td];
#pragma unroll
            for (int i = 0; i < 8; ++i) {
                float q = fq_s[ee][tc * 8 + i];
                acc[i] += q * hv;
            }
        }
#pragma unroll
        for (int j = 0; j < 8; ++j)
            den_part += fq_s[qq * 8 + j][cq] * S_s[f0 + qq * 8 + j];
        __syncthreads();
    }

    den_s[cq][qq] = den_part;
    __syncthreads();
    if (tid < 64)
        yden[(b * C + c0 + tid) * HH + h] =
            den_s[tid][0] + den_s[tid][1] + den_s[tid][2] + den_s[tid][3];

#pragma unroll
    for (int i = 0; i < 8; ++i) {
        int c = c0 + tc * 8 + i;
        int base = ((b * C + c) * HH + h) * D + td * 4;
        *(f32x4*)&ynum[base] = acc[i];
    }
}

// ---------------------------------------------------------------------------
// Kernel 1: update_hs (blocks 0..255) + V copy + FK copy (L3 slice sharing).
// ---------------------------------------------------------------------------
__global__ __launch_bounds__(256) void fused_hs_vfk(
        const float* __restrict__ FKi, const float* __restrict__ Vi,
        const float* __restrict__ Hi,  const float* __restrict__ Si,
        float* __restrict__ Ho,        float* __restrict__ So,
        const f32x4* __restrict__ V4,  const f32x4* __restrict__ vc,  f32x4* __restrict__ oV,
        const f32x4* __restrict__ FK4, const f32x4* __restrict__ fkc, f32x4* __restrict__ oFK,
        const int* __restrict__ wp_p,  const int* __restrict__ valid_p) {
    int wp, num_excess, pos;
    ring_params(wp_p, valid_p, wp, num_excess, pos);

    int bx = blockIdx.x;
    if (bx < HS_BLOCKS) {
        update_hs_body(bx, FKi, Vi, Hi, Si, Ho, So, wp, num_excess);
        return;
    }
    bx -= HS_BLOCKS;
    if (bx < COPY_BLOCKS) {
        ring_copy_block(bx, threadIdx.x, V4, vc, oV, pos);
        return;
    }
    bx -= COPY_BLOCKS;
    ring_copy_block(bx, threadIdx.x, FK4, fkc, oFK, pos);
}

// ---------------------------------------------------------------------------
// Kernel 2: compute_y_den (blocks 0..1023) + K copy.
// ---------------------------------------------------------------------------
__global__ __launch_bounds__(256) void fused_y_k(
        const float* __restrict__ fq, const float* __restrict__ Hn,
        const float* __restrict__ Sn,
        float* __restrict__ ynum,     float* __restrict__ yden,
        const f32x4* __restrict__ K4, const f32x4* __restrict__ kc,
        f32x4* __restrict__ oK,
        const int* __restrict__ wp_p, const int* __restrict__ valid_p) {
    int wp, num_excess, pos;
    ring_params(wp_p, valid_p, wp, num_excess, pos);

    int bx = blockIdx.x;
    if (bx < Y_BLOCKS) {
        compute_y_den_body(bx, fq, Hn, Sn, ynum, yden);
        return;
    }
    bx -= Y_BLOCKS;
    ring_copy_block(bx, threadIdx.x, K4, kc, oK, pos);
}

// ---------------------------------------------------------------------------
extern "C" void kernel_launch(void* const* d_in, const int* in_sizes, int n_in,
                              void* d_out, int out_size, void* d_ws, size_t ws_size,
                              hipStream_t stream) {
    const float* K   = (const float*)d_in[0];
    const float* V   = (const float*)d_in[1];
    const float* FK  = (const float*)d_in[2];
    const float* H   = (const float*)d_in[3];
    const float* S   = (const float*)d_in[4];
    const float* k_c = (const float*)d_in[5];
    const float* v_c = (const float*)d_in[6];
    const float* fk_c= (const float*)d_in[7];
    const float* fq  = (const float*)d_in[8];
    const int* wp    = (const int*)d_in[9];
    const int* valid = (const int*)d_in[10];

    float* out = (float*)d_out;
    float* o_ynum = out + OFF_YNUM;
    float* o_yden = out + OFF_YDEN;
    float* o_K    = out + OFF_K;
    float* o_V    = out + OFF_V;
    float* o_FK   = out + OFF_FK;
    float* o_H    = out + OFF_H;
    float* o_S    = out + OFF_S;

    // Kernel 1: H/S update (depth-2 prefetch) overlapped with V, FK copies.
    fused_hs_vfk<<<HS_BLOCKS + 2 * COPY_BLOCKS, 256, 0, stream>>>(
        FK, V, H, S, o_H, o_S,
        (const f32x4*)V,  (const f32x4*)v_c,  (f32x4*)o_V,
        (const f32x4*)FK, (const f32x4*)fk_c, (f32x4*)o_FK,
        wp, valid);

    // Kernel 2: y_num/y_den (reads H_new, S_new) overlapped with K ring copy.
    fused_y_k<<<Y_BLOCKS + COPY_BLOCKS, 256, 0, stream>>>(
        fq, o_H, o_S, o_ynum, o_yden,
        (const f32x4*)K, (const f32x4*)k_c, (f32x4*)o_K,
        wp, valid);
}